// Round 21
// baseline (61.378 us; speedup 1.0000x reference)
//
#include <hip/hip_runtime.h>

#define TT 16384
#define DD 2048
#define EE 64

typedef __attribute__((ext_vector_type(8))) short bf16x8;
typedef __attribute__((ext_vector_type(8))) unsigned short ushort8;
typedef __attribute__((ext_vector_type(4))) float f32x4;

__device__ __forceinline__ unsigned short bf16_rne(float f) {
    unsigned u = __float_as_uint(f);
    return (unsigned short)((u + 0x7FFFu + ((u >> 16) & 1u)) >> 16);
}
__device__ __forceinline__ float bf16_f32(unsigned short h) {
    return __uint_as_float(((unsigned)h) << 16);
}
__device__ __forceinline__ unsigned cvt_pk(float lo, float hi) {
    unsigned r;
    asm("v_cvt_pk_bf16_f32 %0, %1, %2" : "=v"(r) : "v"(lo), "v"(hi));
    return r;
}
__device__ __forceinline__ bf16x8 pack4(unsigned a, unsigned b, unsigned c, unsigned d) {
    union { unsigned u[4]; bf16x8 v; } t;
    t.u[0] = a; t.u[1] = b; t.u[2] = c; t.u[3] = d;
    return t.v;
}
__device__ __forceinline__ void gload16(void* lds, const void* g) {
    __builtin_amdgcn_global_load_lds(
        (const __attribute__((address_space(1))) unsigned int*)g,
        (__attribute__((address_space(3))) unsigned int*)lds, 16, 0, 0);
}
#define SB0() __builtin_amdgcn_sched_barrier(0)

// ---------------------------------------------------------------------------
// W [2048][64] f32 -> wpack (R5/R13-verified 16x16x32 A-frag layout).
// wpack[K0][h][m][lane][j] = bf16 hi/lo of wg[(K0*32+(lane>>4)*8+j)*64 + m*16+(lane&15)]
__global__ __launch_bounds__(256)
void wconv(const float* __restrict__ wg, unsigned short* __restrict__ wpack) {
    const int t = (int)blockIdx.x * 256 + threadIdx.x;  // 32768 threads
    const int K0 = t >> 9, h = (t >> 8) & 1, m = (t >> 6) & 3, lane = t & 63;
    const int e = m * 16 + (lane & 15);
    const int ks = K0 * 32 + (lane >> 4) * 8;
    ushort8 v;
#pragma unroll
    for (int j = 0; j < 8; ++j) {
        const float f = wg[(size_t)(ks + j) * EE + e];
        const unsigned short hi = bf16_rne(f);
        v[j] = h ? bf16_rne(f - bf16_f32(hi)) : hi;
    }
    *(ushort8*)(wpack + ((size_t)(K0 * 8 + h * 4 + m) * 64 + lane) * 8) = v;
}

// ---------------------------------------------------------------------------
// R19's geometry (32 tok/wave, 2 x 16-token B-tiles share one W set, W L2
// = 256 MB, 128-B x segments) at DOUBLE residency: 2-slot rings shrink LDS
// 48->32 KB so 4 blocks/CU fit -> 16 waves/CU (vs R19's 8).
// Block = 256 thr = 4 waves on the same 32 tokens; wave q owns K-quarter,
// 16 steps x 32 k.  ITER: vmcnt(12) drains {st(s),W(s)}; read slot s&1;
// lgkm fence; stage(s+2)->slot s&1; MFMA set s&1; loadW(s+2)->set s&1
// (consumed-then-reload, R20-verified).  Grid 512.
__global__ __launch_bounds__(256, 4)
void gate_fused(const float* __restrict__ x, const unsigned short* __restrict__ wpack,
                const float* __restrict__ loads, float* __restrict__ out,
                float* __restrict__ binpart) {
    __shared__ __align__(16) float arena[8192];  // 32 KB: 4 waves x 2 x 1024 f
    __shared__ float bins[64];

    const int tid = threadIdx.x, lane = tid & 63, q = tid >> 6;  // K-quarter
    const int tb = (int)blockIdx.x;

    f32x4 a0[4] = {{0,0,0,0},{0,0,0,0},{0,0,0,0},{0,0,0,0}};  // tok 0-15
    f32x4 a1[4] = {{0,0,0,0},{0,0,0,0},{0,0,0,0},{0,0,0,0}};  // tok 16-31

    float* ring = arena + (size_t)q * 2048;
    float *sp0 = ring, *sp1 = ring + 1024;

    // stage step s (32 rows x 32 k = 4 KB): 4 x gload16, 8 rows x 128 B each.
    auto stage_x = [&](int s, float* sb) {
#pragma unroll
        for (int i = 0; i < 4; ++i) {
            const int rowp = lane >> 3;       // 0..7
            const int c = (lane & 7) ^ rowp;  // source-side chunk swizzle
            gload16(sb + i * 256,
                    x + (size_t)(tb * 32 + i * 8 + rowp) * DD + q * 512 + s * 32 + c * 4);
        }
    };
    // 8 W frags for 32-k chunk q*16+s (hi[4] + lo[4]), 1 KB/frag coalesced.
    auto loadW = [&](int s, bf16x8 (&wh)[4], bf16x8 (&wl)[4]) {
        const unsigned short* base = wpack + (size_t)(q * 16 + s) * 4096 + lane * 8;
#pragma unroll
        for (int m = 0; m < 4; ++m) {
            wh[m] = *(const bf16x8*)(base + (size_t)m * 512);
            wl[m] = *(const bf16x8*)(base + (size_t)(4 + m) * 512);
        }
    };
    // both tiles' B-frags (R19-verified; sw identical for r and 16+r).
    auto readx = [&](const float* sb, f32x4& va0, f32x4& vb0, f32x4& va1, f32x4& vb1) {
        const int rl = lane & 15;
        const int kgc = (lane >> 4) << 1;
        const int sw = rl & 7;
        va0 = *(const f32x4*)(sb + rl * 32 + ((kgc) ^ sw) * 4);
        vb0 = *(const f32x4*)(sb + rl * 32 + ((kgc + 1) ^ sw) * 4);
        va1 = *(const f32x4*)(sb + (16 + rl) * 32 + ((kgc) ^ sw) * 4);
        vb1 = *(const f32x4*)(sb + (16 + rl) * 32 + ((kgc + 1) ^ sw) * 4);
    };
    auto domfma = [&](const f32x4& va, const f32x4& vb,
                      bf16x8 (&wh)[4], bf16x8 (&wl)[4], f32x4 (&ac)[4]) {
        const float cf[8] = {va.x, va.y, va.z, va.w, vb.x, vb.y, vb.z, vb.w};
        unsigned ph[4], pl[4];
#pragma unroll
        for (int j = 0; j < 4; ++j) {
            ph[j] = cvt_pk(cf[2 * j], cf[2 * j + 1]);
            const float h0 = __uint_as_float(ph[j] << 16);
            const float h1 = __uint_as_float(ph[j] & 0xFFFF0000u);
            pl[j] = cvt_pk(cf[2 * j] - h0, cf[2 * j + 1] - h1);
        }
        const bf16x8 bhi = pack4(ph[0], ph[1], ph[2], ph[3]);
        const bf16x8 blo = pack4(pl[0], pl[1], pl[2], pl[3]);
#pragma unroll
        for (int m = 0; m < 4; ++m) {
            ac[m] = __builtin_amdgcn_mfma_f32_16x16x32_bf16(wh[m], bhi, ac[m], 0, 0, 0);
            ac[m] = __builtin_amdgcn_mfma_f32_16x16x32_bf16(wh[m], blo, ac[m], 0, 0, 0);
            ac[m] = __builtin_amdgcn_mfma_f32_16x16x32_bf16(wl[m], bhi, ac[m], 0, 0, 0);
        }
    };

    bf16x8 WH0[4], WO0[4], WH1[4], WO1[4];

    // prologue FIFO: st0(4) W0(8) st1(4) W1(8) = 24 outstanding.
    stage_x(0, sp0); SB0();
    loadW(0, WH0, WO0); SB0();
    stage_x(1, sp1); SB0();
    loadW(1, WH1, WO1); SB0();

    // ITER(s): vmcnt(VM) drains {st(s), W(s)}; read slot s&1; lgkm fence;
    // stage(s+2)->slot s&1; MFMA with W set s&1; loadW(s+2)->set s&1.
#define ITER(s, sl, VM, DOW, DOS)                                         \
    do {                                                                  \
        asm volatile("s_waitcnt vmcnt(" #VM ")" ::: "memory"); SB0();     \
        f32x4 va0, vb0, va1, vb1;                                         \
        readx(sp##sl, va0, vb0, va1, vb1); SB0();                         \
        asm volatile("s_waitcnt lgkmcnt(0)" ::: "memory"); SB0();         \
        if (DOS) stage_x((s) + 2, sp##sl);                                \
        SB0();                                                            \
        domfma(va0, vb0, WH##sl, WO##sl, a0);                             \
        domfma(va1, vb1, WH##sl, WO##sl, a1);                             \
        SB0();                                                            \
        if (DOW) loadW((s) + 2, WH##sl, WO##sl);                          \
        SB0();                                                            \
    } while (0)

    ITER(0, 0, 12, 1, 1);  ITER(1, 1, 12, 1, 1);
    ITER(2, 0, 12, 1, 1);  ITER(3, 1, 12, 1, 1);
    ITER(4, 0, 12, 1, 1);  ITER(5, 1, 12, 1, 1);
    ITER(6, 0, 12, 1, 1);  ITER(7, 1, 12, 1, 1);
    ITER(8, 0, 12, 1, 1);  ITER(9, 1, 12, 1, 1);
    ITER(10, 0, 12, 1, 1); ITER(11, 1, 12, 1, 1);
    ITER(12, 0, 12, 1, 1);   // loads W14->set0, stages st14->slot0
    ITER(13, 1, 12, 1, 1);   // loads W15->set1, stages st15->slot1
    ITER(14, 0, 12, 0, 0);   // drains st14+W14; uses W14 (set0), st14
    ITER(15, 1, 0, 0, 0);    // drains st15+W15; uses W15 (set1), st15
#undef ITER

    // ---- 4-way K reduce through arena overlay (stride 36, 32 f/lane) -----
    __syncthreads();
    if (q != 0) {
        float* p = arena + (size_t)(q - 1) * 2304 + lane * 36;
#pragma unroll
        for (int m = 0; m < 4; ++m) {
            *(f32x4*)(p + m * 4) = a0[m];
            *(f32x4*)(p + 16 + m * 4) = a1[m];
        }
    }
    __syncthreads();
    if (q != 0) return;

#pragma unroll 1
    for (int qq = 0; qq < 3; ++qq) {
        const float* p = arena + (size_t)qq * 2304 + lane * 36;
#pragma unroll
        for (int m = 0; m < 4; ++m) {
            const f32x4 t0 = *(const f32x4*)(p + m * 4);
            const f32x4 t1 = *(const f32x4*)(p + 16 + m * 4);
            a0[m].x += t0.x; a0[m].y += t0.y; a0[m].z += t0.z; a0[m].w += t0.w;
            a1[m].x += t1.x; a1[m].y += t1.y; a1[m].z += t1.z; a1[m].w += t1.w;
        }
    }

    // ---- top-2 per tile (R13/R19-verified): e = m*16 + (lane>>4)*4 + rr --
    bins[lane] = 0.0f;
    const int col = lane & 15;
    const int erow = (lane >> 4) * 4;
    auto topk = [&](f32x4 (&r)[4], int tokbase) {
        float v1 = -3.4e38f, u1 = 0.0f, v2 = -3.4e38f, u2 = 0.0f;
        int i1 = 0x7fffffff, i2 = 0x7fffffff;
#pragma unroll
        for (int m = 0; m < 4; ++m)
#pragma unroll
            for (int rr = 0; rr < 4; ++rr) {
                const int e = m * 16 + erow + rr;
                const float u = r[m][rr];
                const float b = u - (loads[e] - 0.015625f) * 2.0f;
                if ((b > v1) || (b == v1 && e < i1)) {
                    v2 = v1; u2 = u1; i2 = i1;
                    v1 = b;  u1 = u;  i1 = e;
                } else if ((b > v2) || (b == v2 && e < i2)) {
                    v2 = b; u2 = u; i2 = e;
                }
            }
#pragma unroll
        for (int s = 0; s < 2; ++s) {
            const int mask = 16 << s;
            const float ov1 = __shfl_xor(v1, mask), ou1 = __shfl_xor(u1, mask);
            const float ov2 = __shfl_xor(v2, mask), ou2 = __shfl_xor(u2, mask);
            const int oi1 = __shfl_xor(i1, mask), oi2 = __shfl_xor(i2, mask);
            if ((ov1 > v1) || (ov1 == v1 && oi1 < i1)) {
                if ((v1 > ov2) || (v1 == ov2 && i1 < oi2)) { v2 = v1; u2 = u1; i2 = i1; }
                else                                        { v2 = ov2; u2 = ou2; i2 = oi2; }
                v1 = ov1; u1 = ou1; i1 = oi1;
            } else if ((ov1 > v2) || (ov1 == v2 && oi1 < i2)) {
                v2 = ov1; u2 = ou1; i2 = oi1;
            }
        }
        if (lane < 16) {
            const int tok = tokbase + col;
            const float mx = fmaxf(u1, u2);
            const float e1 = __expf(u1 - mx), e2 = __expf(u2 - mx);
            const float w1 = e1 / (e1 + e2), w2 = e2 / (e1 + e2);
            *(float2*)(out + 2 * tok) = make_float2(w1, w2);
            *(float2*)(out + 2 * TT + 2 * tok) = make_float2((float)i1, (float)i2);
            atomicAdd(&bins[i1], w1);
            atomicAdd(&bins[i2], w2);
        }
    };
    topk(a0, tb * 32);
    topk(a1, tb * 32 + 16);

    binpart[(size_t)tb * 64 + lane] = bins[lane];
}

// ---------------------------------------------------------------------------
// Merged finalize: 1 block x 1024 thr sums [512][64] rows (fixed order) + EMA.
__global__ __launch_bounds__(1024)
void finalize(const float* __restrict__ binpart, const float* __restrict__ loads,
              float* __restrict__ out) {
    __shared__ float p[16][64];
    const int e = threadIdx.x & 63, sub = threadIdx.x >> 6;  // 0..15
    float s = 0.0f;
#pragma unroll
    for (int r = 0; r < 32; ++r)
        s += binpart[(size_t)(sub * 32 + r) * 64 + e];
    p[sub][e] = s;
    __syncthreads();
    if (sub == 0) {
        float tot = 0.0f;
#pragma unroll
        for (int k = 0; k < 16; ++k) tot += p[k][e];
        out[4 * TT + e] = 0.9f * loads[e] + 0.1f * (tot * (1.0f / 16384.0f));
    }
}

// ---------------------------------------------------------------------------
extern "C" void kernel_launch(void* const* d_in, const int* in_sizes, int n_in,
                              void* d_out, int out_size, void* d_ws, size_t ws_size,
                              hipStream_t stream) {
    const float* x = (const float*)d_in[0];      // [16384, 2048]
    const float* wg = (const float*)d_in[1];     // [2048, 64]
    const float* loads = (const float*)d_in[2];  // [64]
    float* out = (float*)d_out;

    unsigned short* wpack = (unsigned short*)d_ws;               // 512 KB
    float* binpart = (float*)(wpack + (size_t)64 * 8 * 64 * 8);  // [512][64]

    hipLaunchKernelGGL(wconv, dim3(128), dim3(256), 0, stream, wg, wpack);
    hipLaunchKernelGGL(gate_fused, dim3(512), dim3(256), 0, stream,
                       x, wpack, loads, out, binpart);
    hipLaunchKernelGGL(finalize, dim3(1), dim3(1024), 0, stream,
                       binpart, loads, out);
}

// Round 22
// 40.004 us; speedup vs baseline: 1.5343x; 1.5343x over previous
//
#include <hip/hip_runtime.h>

#define TT 16384
#define DD 2048
#define EE 64

typedef __attribute__((ext_vector_type(8))) short bf16x8;
typedef __attribute__((ext_vector_type(8))) unsigned short ushort8;
typedef __attribute__((ext_vector_type(4))) float f32x4;

__device__ __forceinline__ unsigned short bf16_rne(float f) {
    unsigned u = __float_as_uint(f);
    return (unsigned short)((u + 0x7FFFu + ((u >> 16) & 1u)) >> 16);
}
__device__ __forceinline__ float bf16_f32(unsigned short h) {
    return __uint_as_float(((unsigned)h) << 16);
}
__device__ __forceinline__ unsigned cvt_pk(float lo, float hi) {
    unsigned r;
    asm("v_cvt_pk_bf16_f32 %0, %1, %2" : "=v"(r) : "v"(lo), "v"(hi));
    return r;
}
__device__ __forceinline__ bf16x8 pack4(unsigned a, unsigned b, unsigned c, unsigned d) {
    union { unsigned u[4]; bf16x8 v; } t;
    t.u[0] = a; t.u[1] = b; t.u[2] = c; t.u[3] = d;
    return t.v;
}
__device__ __forceinline__ void gload16(void* lds, const void* g) {
    __builtin_amdgcn_global_load_lds(
        (const __attribute__((address_space(1))) unsigned int*)g,
        (__attribute__((address_space(3))) unsigned int*)lds, 16, 0, 0);
}
#define SB0() __builtin_amdgcn_sched_barrier(0)

// ---------------------------------------------------------------------------
// W [2048][64] f32 -> wpack (R5/R13-verified 16x16x32 A-frag layout).
// wpack[K0][h][m][lane][j] = bf16 hi/lo of wg[(K0*32+(lane>>4)*8+j)*64 + m*16+(lane&15)]
__global__ __launch_bounds__(256)
void wconv(const float* __restrict__ wg, unsigned short* __restrict__ wpack) {
    const int t = (int)blockIdx.x * 256 + threadIdx.x;  // 32768 threads
    const int K0 = t >> 9, h = (t >> 8) & 1, m = (t >> 6) & 3, lane = t & 63;
    const int e = m * 16 + (lane & 15);
    const int ks = K0 * 32 + (lane >> 4) * 8;
    ushort8 v;
#pragma unroll
    for (int j = 0; j < 8; ++j) {
        const float f = wg[(size_t)(ks + j) * EE + e];
        const unsigned short hi = bf16_rne(f);
        v[j] = h ? bf16_rne(f - bf16_f32(hi)) : hi;
    }
    *(ushort8*)(wpack + ((size_t)(K0 * 8 + h * 4 + m) * 64 + lane) * 8) = v;
}

// ---------------------------------------------------------------------------
// R19 verbatim -- the verified session optimum (40.2 us total).
// 32 tokens per wave (2 x 16-token B-tiles share one W frag set -> W L2
// traffic 256 MB), 128-B x staging segments.  Block = 256 thr = 4 waves on
// the same 32 tokens; wave q owns K-quarter [q*512,+512), 16 steps x 32 k.
// Staging fully wave-private (3-slot 4 KB ring each, 48 KB total) -> NO
// K-loop barriers.  W: 3 named register sets loaded 2 steps ahead.  Steady
// vmcnt(16) drains exactly {st(s), W(s)}.  Grid 512 = 2 blocks/CU.
__global__ __launch_bounds__(256, 2)
void gate_fused(const float* __restrict__ x, const unsigned short* __restrict__ wpack,
                const float* __restrict__ loads, float* __restrict__ out,
                float* __restrict__ binpart) {
    __shared__ __align__(16) float arena[12288];  // 48 KB: 4 waves x 3 x 1024 f
    __shared__ float bins[64];

    const int tid = threadIdx.x, lane = tid & 63, q = tid >> 6;  // K-quarter
    const int tb = (int)blockIdx.x;

    f32x4 a0[4] = {{0,0,0,0},{0,0,0,0},{0,0,0,0},{0,0,0,0}};  // tile 0 (tok 0-15)
    f32x4 a1[4] = {{0,0,0,0},{0,0,0,0},{0,0,0,0},{0,0,0,0}};  // tile 1 (tok 16-31)

    float* ring = arena + (size_t)q * 3072;
    float *sp0 = ring, *sp1 = ring + 1024, *sp2 = ring + 2048;

    // stage step s (32 rows x 32 k = 4 KB): 4 x gload16, 8 rows x 128 B each.
    auto stage_x = [&](int s, float* sb) {
#pragma unroll
        for (int i = 0; i < 4; ++i) {
            const int rowp = lane >> 3;       // 0..7
            const int c = (lane & 7) ^ rowp;  // source-side chunk swizzle
            gload16(sb + i * 256,
                    x + (size_t)(tb * 32 + i * 8 + rowp) * DD + q * 512 + s * 32 + c * 4);
        }
    };
    // 8 W frags for 32-k chunk kc = q*16 + s (hi[4] + lo[4]), 1 KB/frag.
    auto loadW = [&](int s, bf16x8 (&wh)[4], bf16x8 (&wl)[4]) {
        const unsigned short* base = wpack + (size_t)(q * 16 + s) * 4096 + lane * 8;
#pragma unroll
        for (int m = 0; m < 4; ++m) {
            wh[m] = *(const bf16x8*)(base + (size_t)m * 512);
            wl[m] = *(const bf16x8*)(base + (size_t)(4 + m) * 512);
        }
    };
    // read both tiles' B-frags (sw identical for r and 16+r since 16%8==0).
    auto readx = [&](const float* sb, f32x4& va0, f32x4& vb0, f32x4& va1, f32x4& vb1) {
        const int rl = lane & 15;
        const int kgc = (lane >> 4) << 1;
        const int sw = rl & 7;
        va0 = *(const f32x4*)(sb + rl * 32 + ((kgc) ^ sw) * 4);
        vb0 = *(const f32x4*)(sb + rl * 32 + ((kgc + 1) ^ sw) * 4);
        va1 = *(const f32x4*)(sb + (16 + rl) * 32 + ((kgc) ^ sw) * 4);
        vb1 = *(const f32x4*)(sb + (16 + rl) * 32 + ((kgc + 1) ^ sw) * 4);
    };
    auto domfma = [&](const f32x4& va, const f32x4& vb,
                      bf16x8 (&wh)[4], bf16x8 (&wl)[4], f32x4 (&ac)[4]) {
        const float cf[8] = {va.x, va.y, va.z, va.w, vb.x, vb.y, vb.z, vb.w};
        unsigned ph[4], pl[4];
#pragma unroll
        for (int j = 0; j < 4; ++j) {
            ph[j] = cvt_pk(cf[2 * j], cf[2 * j + 1]);
            const float h0 = __uint_as_float(ph[j] << 16);
            const float h1 = __uint_as_float(ph[j] & 0xFFFF0000u);
            pl[j] = cvt_pk(cf[2 * j] - h0, cf[2 * j + 1] - h1);
        }
        const bf16x8 bhi = pack4(ph[0], ph[1], ph[2], ph[3]);
        const bf16x8 blo = pack4(pl[0], pl[1], pl[2], pl[3]);
#pragma unroll
        for (int m = 0; m < 4; ++m) {
            ac[m] = __builtin_amdgcn_mfma_f32_16x16x32_bf16(wh[m], bhi, ac[m], 0, 0, 0);
            ac[m] = __builtin_amdgcn_mfma_f32_16x16x32_bf16(wh[m], blo, ac[m], 0, 0, 0);
            ac[m] = __builtin_amdgcn_mfma_f32_16x16x32_bf16(wl[m], bhi, ac[m], 0, 0, 0);
        }
    };

    bf16x8 WH0[4], WO0[4], WH1[4], WO1[4], WH2[4], WO2[4];

    // prologue FIFO: st0(4) W0(8) st1(4) W1(8) st2(4) = 28
    stage_x(0, sp0); SB0();
    loadW(0, WH0, WO0); SB0();
    stage_x(1, sp1); SB0();
    loadW(1, WH1, WO1); SB0();
    stage_x(2, sp2); SB0();

    // ITER(s): vmcnt(VM) drains {st(s),W(s)}; read slot s%3; fence; issue
    // W(s+2)->buf (s+2)%3 and st(s+3)->slot s%3; MFMA with W buf s%3.
#define ITER(s, nsl, nwl, VM, DOW, DOS)                                   \
    do {                                                                  \
        asm volatile("s_waitcnt vmcnt(" #VM ")" ::: "memory"); SB0();     \
        f32x4 va0, vb0, va1, vb1;                                         \
        readx(sp##nsl, va0, vb0, va1, vb1); SB0();                        \
        asm volatile("s_waitcnt lgkmcnt(0)" ::: "memory"); SB0();         \
        if (DOW) loadW((s) + 2, WH##nwl, WO##nwl);                        \
        SB0();                                                            \
        if (DOS) stage_x((s) + 3, sp##nsl);                               \
        SB0();                                                            \
        domfma(va0, vb0, WH##nsl, WO##nsl, a0);                           \
        domfma(va1, vb1, WH##nsl, WO##nsl, a1);                           \
    } while (0)

    ITER(0, 0, 2, 16, 1, 1);  ITER(1, 1, 0, 16, 1, 1);
    ITER(2, 2, 1, 16, 1, 1);  ITER(3, 0, 2, 16, 1, 1);
    ITER(4, 1, 0, 16, 1, 1);  ITER(5, 2, 1, 16, 1, 1);
    ITER(6, 0, 2, 16, 1, 1);  ITER(7, 1, 0, 16, 1, 1);
    ITER(8, 2, 1, 16, 1, 1);  ITER(9, 0, 2, 16, 1, 1);
    ITER(10, 1, 0, 16, 1, 1); ITER(11, 2, 1, 16, 1, 1);
    ITER(12, 0, 2, 16, 1, 1);               // loads W14->buf2, stages st15->slot0
    ITER(13, 1, 0, 16, 1, 0);               // loads W15->buf0, no stage
    ITER(14, 2, 0, 12, 0, 0);               // DOW=0: WH0 paste valid, unused
    ITER(15, 0, 0, 0, 0, 0);
#undef ITER

    // ---- 4-way K reduce through arena overlay (stride 36, 32 f/lane) -----
    __syncthreads();
    if (q != 0) {
        float* p = arena + (size_t)(q - 1) * 2304 + lane * 36;
#pragma unroll
        for (int m = 0; m < 4; ++m) {
            *(f32x4*)(p + m * 4) = a0[m];
            *(f32x4*)(p + 16 + m * 4) = a1[m];
        }
    }
    __syncthreads();
    if (q != 0) return;

#pragma unroll 1
    for (int qq = 0; qq < 3; ++qq) {
        const float* p = arena + (size_t)qq * 2304 + lane * 36;
#pragma unroll
        for (int m = 0; m < 4; ++m) {
            const f32x4 t0 = *(const f32x4*)(p + m * 4);
            const f32x4 t1 = *(const f32x4*)(p + 16 + m * 4);
            a0[m].x += t0.x; a0[m].y += t0.y; a0[m].z += t0.z; a0[m].w += t0.w;
            a1[m].x += t1.x; a1[m].y += t1.y; a1[m].z += t1.z; a1[m].w += t1.w;
        }
    }

    // ---- top-2 per tile (R13-verified): e = m*16 + (lane>>4)*4 + rr ------
    bins[lane] = 0.0f;
    const int col = lane & 15;
    const int erow = (lane >> 4) * 4;
    auto topk = [&](f32x4 (&r)[4], int tokbase) {
        float v1 = -3.4e38f, u1 = 0.0f, v2 = -3.4e38f, u2 = 0.0f;
        int i1 = 0x7fffffff, i2 = 0x7fffffff;
#pragma unroll
        for (int m = 0; m < 4; ++m)
#pragma unroll
            for (int rr = 0; rr < 4; ++rr) {
                const int e = m * 16 + erow + rr;
                const float u = r[m][rr];
                const float b = u - (loads[e] - 0.015625f) * 2.0f;
                if ((b > v1) || (b == v1 && e < i1)) {
                    v2 = v1; u2 = u1; i2 = i1;
                    v1 = b;  u1 = u;  i1 = e;
                } else if ((b > v2) || (b == v2 && e < i2)) {
                    v2 = b; u2 = u; i2 = e;
                }
            }
#pragma unroll
        for (int s = 0; s < 2; ++s) {
            const int mask = 16 << s;
            const float ov1 = __shfl_xor(v1, mask), ou1 = __shfl_xor(u1, mask);
            const float ov2 = __shfl_xor(v2, mask), ou2 = __shfl_xor(u2, mask);
            const int oi1 = __shfl_xor(i1, mask), oi2 = __shfl_xor(i2, mask);
            if ((ov1 > v1) || (ov1 == v1 && oi1 < i1)) {
                if ((v1 > ov2) || (v1 == ov2 && i1 < oi2)) { v2 = v1; u2 = u1; i2 = i1; }
                else                                        { v2 = ov2; u2 = ou2; i2 = oi2; }
                v1 = ov1; u1 = ou1; i1 = oi1;
            } else if ((ov1 > v2) || (ov1 == v2 && oi1 < i2)) {
                v2 = ov1; u2 = ou1; i2 = oi1;
            }
        }
        if (lane < 16) {
            const int tok = tokbase + col;
            const float mx = fmaxf(u1, u2);
            const float e1 = __expf(u1 - mx), e2 = __expf(u2 - mx);
            const float w1 = e1 / (e1 + e2), w2 = e2 / (e1 + e2);
            *(float2*)(out + 2 * tok) = make_float2(w1, w2);
            *(float2*)(out + 2 * TT + 2 * tok) = make_float2((float)i1, (float)i2);
            atomicAdd(&bins[i1], w1);
            atomicAdd(&bins[i2], w2);
        }
    };
    topk(a0, tb * 32);
    topk(a1, tb * 32 + 16);

    binpart[(size_t)tb * 64 + lane] = bins[lane];
}

// ---------------------------------------------------------------------------
// Merged finalize: 1 block x 1024 thr sums [512][64] rows (fixed order) + EMA.
__global__ __launch_bounds__(1024)
void finalize(const float* __restrict__ binpart, const float* __restrict__ loads,
              float* __restrict__ out) {
    __shared__ float p[16][64];
    const int e = threadIdx.x & 63, sub = threadIdx.x >> 6;  // 0..15
    float s = 0.0f;
#pragma unroll
    for (int r = 0; r < 32; ++r)
        s += binpart[(size_t)(sub * 32 + r) * 64 + e];
    p[sub][e] = s;
    __syncthreads();
    if (sub == 0) {
        float tot = 0.0f;
#pragma unroll
        for (int k = 0; k < 16; ++k) tot += p[k][e];
        out[4 * TT + e] = 0.9f * loads[e] + 0.1f * (tot * (1.0f / 16384.0f));
    }
}

// ---------------------------------------------------------------------------
extern "C" void kernel_launch(void* const* d_in, const int* in_sizes, int n_in,
                              void* d_out, int out_size, void* d_ws, size_t ws_size,
                              hipStream_t stream) {
    const float* x = (const float*)d_in[0];      // [16384, 2048]
    const float* wg = (const float*)d_in[1];     // [2048, 64]
    const float* loads = (const float*)d_in[2];  // [64]
    float* out = (float*)d_out;

    unsigned short* wpack = (unsigned short*)d_ws;               // 512 KB
    float* binpart = (float*)(wpack + (size_t)64 * 8 * 64 * 8);  // [512][64]

    hipLaunchKernelGGL(wconv, dim3(128), dim3(256), 0, stream, wg, wpack);
    hipLaunchKernelGGL(gate_fused, dim3(512), dim3(256), 0, stream,
                       x, wpack, loads, out, binpart);
    hipLaunchKernelGGL(finalize, dim3(1), dim3(1024), 0, stream,
                       binpart, loads, out);
}